// Round 7
// baseline (4075.266 us; speedup 1.0000x reference)
//
#include <hip/hip_runtime.h>
#include <stdint.h>

// Problem constants
constexpr int N  = 20000;    // nodes
constexpr int E  = 320000;   // edges
constexpr int H  = 256;      // hidden
constexpr int FEAT = 64;     // FE == FV
constexpr int NL = 4;        // layers
constexpr int FL = 1024;

typedef unsigned short u16;
typedef short bf16x8 __attribute__((ext_vector_type(8)));
typedef float f32x4 __attribute__((ext_vector_type(4)));

// ---------------- bf16 helpers (manual, RNE) ----------------
__device__ __forceinline__ float bf2f(u16 u) {
    union { uint32_t i; float f; } v; v.i = ((uint32_t)u) << 16; return v.f;
}
__device__ __forceinline__ u16 f2bf(float f) {
    union { uint32_t i; float f; } v; v.f = f;
    uint32_t r = v.i + 0x7FFFu + ((v.i >> 16) & 1u);
    return (u16)(r >> 16);
}
__device__ __forceinline__ float sigmf(float x) { return 1.f / (1.f + __expf(-x)); }
__device__ __forceinline__ float tanhf_(float x) { return 2.f / (1.f + __expf(-2.f * x)) - 1.f; }

// packed bf16 pair add: (2 bf16 in u32) + (2 bf16 in u32) -> 2 bf16
__device__ __forceinline__ uint32_t addbf2(uint32_t a, uint32_t b) {
    union { uint32_t i; float f; } al, ah, bl, bh;
    al.i = a << 16; ah.i = a & 0xFFFF0000u;
    bl.i = b << 16; bh.i = b & 0xFFFF0000u;
    return ((uint32_t)f2bf(al.f + bl.f)) | (((uint32_t)f2bf(ah.f + bh.f)) << 16);
}
__device__ __forceinline__ uint4 addbf8(uint4 a, uint4 b) {
    return make_uint4(addbf2(a.x, b.x), addbf2(a.y, b.y), addbf2(a.z, b.z), addbf2(a.w, b.w));
}

// order-preserving float<->u32 encoding (for atomic max over signed floats)
__device__ __forceinline__ unsigned int encf(float x) {
    unsigned int u = __float_as_uint(x);
    return (u & 0x80000000u) ? ~u : (u | 0x80000000u);
}
__device__ __forceinline__ float decf(unsigned int k) {
    unsigned int u = (k & 0x80000000u) ? (k ^ 0x80000000u) : ~k;
    return __uint_as_float(u);
}

// B-fragment load: bf16 direct, or fp32 + inline convert (fallback when ws too small)
template <bool W16>
__device__ __forceinline__ bf16x8 ldb(const u16* wb, const float* wf, size_t off) {
    if constexpr (W16) {
        return *(const bf16x8*)(wb + off);
    } else {
        float4 b0 = *(const float4*)(wf + off);
        float4 b1 = *(const float4*)(wf + off + 4);
        bf16x8 r;
        r[0] = (short)f2bf(b0.x); r[1] = (short)f2bf(b0.y);
        r[2] = (short)f2bf(b0.z); r[3] = (short)f2bf(b0.w);
        r[4] = (short)f2bf(b1.x); r[5] = (short)f2bf(b1.y);
        r[6] = (short)f2bf(b1.z); r[7] = (short)f2bf(b1.w);
        return r;
    }
}

// ---------------- K0: fuse fin+out linear layers ----------------
__global__ void k_fuse_final(const float* __restrict__ fin_w, const float* __restrict__ fin_b,
                             const float* __restrict__ out_w, const float* __restrict__ out_b,
                             float* __restrict__ w_fo) {
    int h = threadIdx.x;
    float acc = 0.f;
    for (int f = 0; f < FL; ++f) acc = fmaf(out_w[f], fin_w[(size_t)f * H + h], acc);
    w_fo[h] = acc;
    if (h == 0) {
        float b = 0.f;
        for (int f = 0; f < FL; ++f) b = fmaf(out_w[f], fin_b[f], b);
        w_fo[H] = b + out_b[0];
    }
}

// ---------------- weight convert fp32 -> bf16 ----------------
__global__ void k_cvt_w(const float* __restrict__ w, u16* __restrict__ o, int n4) {
    int i = blockIdx.x * 256 + threadIdx.x;
    if (i < n4) {
        float4 v = *(const float4*)(w + (size_t)i * 4);
        *(ushort4*)(o + (size_t)i * 4) = make_ushort4(f2bf(v.x), f2bf(v.y), f2bf(v.z), f2bf(v.w));
    }
}
// combined edge weights: o[l][n][k] = k<256 ? Le[l][n][k] : Lv[l][n][k-256]   (bf16)
__global__ void k_cvt_comb(const float* __restrict__ Le, const float* __restrict__ Lv,
                           u16* __restrict__ o) {
    int i = blockIdx.x * 256 + threadIdx.x;           // NL*256*512/4 quads
    if (i >= NL * 256 * 128) return;
    int idx = i * 4;
    int l = idx >> 17;                 // / (256*512)
    int rem = idx & (256 * 512 - 1);
    int n = rem >> 9, k = rem & 511;
    const float* s = (k < 256) ? (Le + (((size_t)l * 256 + n) << 8) + k)
                               : (Lv + (((size_t)l * 256 + n) << 8) + (k - 256));
    float4 v = *(const float4*)s;
    *(ushort4*)(o + idx) = make_ushort4(f2bf(v.x), f2bf(v.y), f2bf(v.z), f2bf(v.w));
}

// ---------------- CSR build (dual: by src and by dst) ----------------
__global__ void k_zero_int(int* __restrict__ p, int n) {
    int i = blockIdx.x * 256 + threadIdx.x;
    if (i < n) p[i] = 0;
}
__global__ void k_zero_f64(double* __restrict__ p, int n) {
    int i = blockIdx.x * 256 + threadIdx.x;
    if (i < n) p[i] = 0.0;
}
__global__ void k_hist2(const int* __restrict__ src, const int* __restrict__ dst,
                        int* __restrict__ curS, int* __restrict__ curD) {
    int e = blockIdx.x * 256 + threadIdx.x;
    if (e < E) { atomicAdd(&curS[src[e]], 1); atomicAdd(&curD[dst[e]], 1); }
}
__global__ void k_scan(int* __restrict__ cur) {
    __shared__ int cs[256];
    int t = threadIdx.x;
    constexpr int CH = (N + 255) / 256;
    int beg = t * CH, end = min(beg + CH, N);
    int s = 0;
    for (int i = beg; i < end; ++i) s += cur[i];
    cs[t] = s;
    __syncthreads();
    for (int off = 1; off < 256; off <<= 1) {
        int v = cs[t];
        int u = (t >= off) ? cs[t - off] : 0;
        __syncthreads();
        cs[t] = v + u;
        __syncthreads();
    }
    int run = (t > 0) ? cs[t - 1] : 0;
    for (int i = beg; i < end; ++i) { int d = cur[i]; cur[i] = run; run += d; }
}
__global__ void k_fill_pair(const int* __restrict__ src, const int* __restrict__ dst,
                            int* __restrict__ curS, int* __restrict__ curD,
                            int* __restrict__ adjS, int* __restrict__ adjD) {
    int e = blockIdx.x * 256 + threadIdx.x;
    if (e < E) {
        int p = atomicAdd(&curS[src[e]], 1); adjS[p] = e;
        int q = atomicAdd(&curD[dst[e]], 1); adjD[q] = e;
    }
    // after this kernel, curS[v]/curD[v] are END offsets of node v
}
__global__ void k_fill_u32(unsigned int* __restrict__ p, unsigned int val) {
    size_t i = ((size_t)blockIdx.x * 256 + threadIdx.x) * 4;
    uint4 v = make_uint4(val, val, val, val);
    *(uint4*)(p + i) = v;
}

// ---------------- MFMA input projection: C[M,256] = A[M,64] @ W[256,64]^T + b, bf16 out ----------------
template <bool W16>
__global__ __launch_bounds__(256, 3) void k_proj_mfma(
    const float* __restrict__ A, const u16* __restrict__ wb, const float* __restrict__ wf,
    const float* __restrict__ bias, u16* __restrict__ C, int M)
{
    __shared__ u16 As[64][72];
    int t = threadIdx.x;
    int row0 = blockIdx.x * 64;
    int r = t >> 2, q = t & 3;
    if (row0 + r < M) {
        const float* gp = A + (size_t)(row0 + r) * FEAT + q * 16;
#pragma unroll
        for (int i = 0; i < 4; ++i) {
            float4 v = *(const float4*)(gp + i * 4);
            *(ushort4*)&As[r][q * 16 + i * 4] = make_ushort4(f2bf(v.x), f2bf(v.y), f2bf(v.z), f2bf(v.w));
        }
    } else {
#pragma unroll
        for (int i = 0; i < 4; ++i) *(ushort4*)&As[r][q * 16 + i * 4] = make_ushort4(0, 0, 0, 0);
    }
    __syncthreads();
    int w = t >> 6, l = t & 63, lane16 = l & 15, quad = l >> 4;
    f32x4 acc[4][4];
#pragma unroll
    for (int i = 0; i < 4; ++i)
#pragma unroll
        for (int j = 0; j < 4; ++j) acc[i][j] = (f32x4){0.f, 0.f, 0.f, 0.f};
#pragma unroll
    for (int k0 = 0; k0 < FEAT; k0 += 32) {
        bf16x8 a[4], b[4];
#pragma unroll
        for (int mt = 0; mt < 4; ++mt)
            a[mt] = *(const bf16x8*)&As[mt * 16 + lane16][k0 + quad * 8];
#pragma unroll
        for (int nt = 0; nt < 4; ++nt)
            b[nt] = ldb<W16>(wb, wf, (size_t)(w * 16 + nt * 64 + lane16) * FEAT + k0 + quad * 8);
#pragma unroll
        for (int mt = 0; mt < 4; ++mt)
#pragma unroll
            for (int nt = 0; nt < 4; ++nt)
                acc[mt][nt] = __builtin_amdgcn_mfma_f32_16x16x32_bf16(a[mt], b[nt], acc[mt][nt], 0, 0, 0);
    }
#pragma unroll
    for (int nt = 0; nt < 4; ++nt) {
        int col = w * 16 + nt * 64 + lane16;
        float bv = bias[col];
#pragma unroll
        for (int mt = 0; mt < 4; ++mt)
#pragma unroll
            for (int reg = 0; reg < 4; ++reg) {
                int row = mt * 16 + quad * 4 + reg;
                if (row0 + row < M)
                    C[(size_t)(row0 + row) * H + col] = f2bf(acc[mt][nt][reg] + bv);
            }
    }
}

// ---------------- MFMA edge pass v4: fused K=512 GEMM, M-tile 32, 4 blocks/CU ----------------
// raw[e][n] = ([e_in[e] | v_in[src]+v_in[dst]] @ [Le_w | Lv_w]^T)[n]
// FIRST (dst CSR): BN stats (shuffle -> 64-slice global f64 atomics) + raw segmented max.
// !FIRST (src CSR): raw segmented max + e_in += relu(affine(raw)) (tile owns its rows).
template <bool FIRST>
__global__ __launch_bounds__(256, 4) void k_edge_mfma(
    const u16* __restrict__ ein, const u16* __restrict__ wcomb,
    const u16* __restrict__ v_in, const int* __restrict__ src, const int* __restrict__ dst,
    const int* __restrict__ adj, const int* __restrict__ endo,
    unsigned int* __restrict__ vie, double* __restrict__ stats_e,
    const float* __restrict__ scale, const float* __restrict__ shift,
    u16* __restrict__ ein_rw)
{
    __shared__ u16 As[32][520];      // cols 0..255 = e_in row; 256..511 = v_in[src]+v_in[dst]; pad 8
    __shared__ int s_node[32];
    u16 (*praw)[520] = As;           // epilogue aliases cols 0..255

    int t = threadIdx.x;
    int p0 = blockIdx.x * 32;
    int r = t >> 3, q = t & 7;       // r: row 0..31, q: 32-col chunk
    int e_r = adj[p0 + r];           // 8-way redundant, L1 broadcast
    int s_r = src[e_r], d_r = dst[e_r];
    // stage: e_in chunk + bf16 sum of v_in[src], v_in[dst]
    {
        const u16* ep = ein + (size_t)e_r * H + q * 32;
        const u16* sp = v_in + (size_t)s_r * H + q * 32;
        const u16* dp = v_in + (size_t)d_r * H + q * 32;
#pragma unroll
        for (int i = 0; i < 4; ++i)
            *(uint4*)&As[r][q * 32 + i * 8] = *(const uint4*)(ep + i * 8);
#pragma unroll
        for (int i = 0; i < 4; ++i) {
            uint4 sv = *(const uint4*)(sp + i * 8);
            uint4 dv = *(const uint4*)(dp + i * 8);
            *(uint4*)&As[r][256 + q * 32 + i * 8] = addbf8(sv, dv);
        }
    }
    // node-of-position (binary search over END offsets), overlapped with staging loads
    if (t < 32) {
        int lo = 0, hi = N - 1, p = p0 + t;
        while (lo < hi) { int mid = (lo + hi) >> 1; if (endo[mid] > p) hi = mid; else lo = mid + 1; }
        s_node[t] = lo;
    }
    __syncthreads();

    int w = t >> 6, l = t & 63, lane16 = l & 15, quad = l >> 4;
    f32x4 acc[2][4];
#pragma unroll
    for (int i = 0; i < 2; ++i)
#pragma unroll
        for (int j = 0; j < 4; ++j) acc[i][j] = (f32x4){0.f, 0.f, 0.f, 0.f};
    const u16* wb0 = wcomb + ((size_t)(w * 64 + lane16) << 9) + quad * 8;   // stride 512
    for (int k0 = 0; k0 < 512; k0 += 32) {
        bf16x8 a0 = *(const bf16x8*)&As[lane16][k0 + quad * 8];
        bf16x8 a1 = *(const bf16x8*)&As[16 + lane16][k0 + quad * 8];
        bf16x8 b[4];
#pragma unroll
        for (int nt = 0; nt < 4; ++nt)
            b[nt] = *(const bf16x8*)(wb0 + ((size_t)nt << 13) + k0);        // nt*16*512
#pragma unroll
        for (int nt = 0; nt < 4; ++nt) {
            acc[0][nt] = __builtin_amdgcn_mfma_f32_16x16x32_bf16(a0, b[nt], acc[0][nt], 0, 0, 0);
            acc[1][nt] = __builtin_amdgcn_mfma_f32_16x16x32_bf16(a1, b[nt], acc[1][nt], 0, 0, 0);
        }
    }
    __syncthreads();   // As reads complete -> cols 0..255 become praw

#pragma unroll
    for (int nt = 0; nt < 4; ++nt) {
        int col = w * 64 + nt * 16 + lane16;
        float s = 0.f, qq = 0.f;
#pragma unroll
        for (int mt = 0; mt < 2; ++mt)
#pragma unroll
            for (int reg = 0; reg < 4; ++reg) {
                int row = mt * 16 + quad * 4 + reg;
                float v = acc[mt][nt][reg];
                praw[row][col] = f2bf(v);
                if (FIRST) { s += v; qq += v * v; }
            }
        if (FIRST) {
            s  += __shfl_xor(s, 16, 64);  s  += __shfl_xor(s, 32, 64);
            qq += __shfl_xor(qq, 16, 64); qq += __shfl_xor(qq, 32, 64);
            if (quad == 0) {
                int slice = blockIdx.x & 63;
                atomicAdd(&stats_e[(size_t)slice * 512 + col], (double)s);
                atomicAdd(&stats_e[(size_t)slice * 512 + 256 + col], (double)qq);
            }
        }
    }
    __syncthreads();
    // segmented max walk: thread t<128 owns column pair (2t, 2t+1), b32 reads
    if (t < 128) {
        int c2 = t * 2;
        int cur = s_node[0];
        uint32_t pv = *(const uint32_t*)&As[0][c2];
        float m0 = bf2f((u16)(pv & 0xFFFF)), m1 = bf2f((u16)(pv >> 16));
        for (int rr = 1; rr < 32; ++rr) {
            int nd = s_node[rr];
            pv = *(const uint32_t*)&As[rr][c2];
            float v0 = bf2f((u16)(pv & 0xFFFF)), v1 = bf2f((u16)(pv >> 16));
            if (nd != cur) {
                atomicMax(&vie[(size_t)cur * H + c2], encf(m0));
                atomicMax(&vie[(size_t)cur * H + c2 + 1], encf(m1));
                cur = nd; m0 = v0; m1 = v1;
            } else { m0 = fmaxf(m0, v0); m1 = fmaxf(m1, v1); }
        }
        atomicMax(&vie[(size_t)cur * H + c2], encf(m0));
        atomicMax(&vie[(size_t)cur * H + c2 + 1], encf(m1));
    }
    if (!FIRST) {
        // residual: e_in += relu(affine(raw)), uint4 global RMW, b64 praw reads
        u16* gp = ein_rw + (size_t)e_r * H + q * 32;
        const float* scp = scale + q * 32;
        const float* shp = shift + q * 32;
#pragma unroll
        for (int i = 0; i < 4; ++i) {
            int c = q * 32 + i * 8;
            ushort4 pa = *(const ushort4*)&As[r][c];
            ushort4 pb = *(const ushort4*)&As[r][c + 4];
            float4 sc0 = *(const float4*)(scp + i * 8);
            float4 sh0 = *(const float4*)(shp + i * 8);
            float4 sc1 = *(const float4*)(scp + i * 8 + 4);
            float4 sh1 = *(const float4*)(shp + i * 8 + 4);
            uint4 ev = *(const uint4*)(gp + i * 8);
            ushort4 e0 = make_ushort4((u16)(ev.x & 0xFFFF), (u16)(ev.x >> 16),
                                      (u16)(ev.y & 0xFFFF), (u16)(ev.y >> 16));
            ushort4 e1 = make_ushort4((u16)(ev.z & 0xFFFF), (u16)(ev.z >> 16),
                                      (u16)(ev.w & 0xFFFF), (u16)(ev.w >> 16));
            u16 o0 = f2bf(bf2f(e0.x) + fmaxf(fmaf(bf2f(pa.x), sc0.x, sh0.x), 0.f));
            u16 o1 = f2bf(bf2f(e0.y) + fmaxf(fmaf(bf2f(pa.y), sc0.y, sh0.y), 0.f));
            u16 o2 = f2bf(bf2f(e0.z) + fmaxf(fmaf(bf2f(pa.z), sc0.z, sh0.z), 0.f));
            u16 o3 = f2bf(bf2f(e0.w) + fmaxf(fmaf(bf2f(pa.w), sc0.w, sh0.w), 0.f));
            u16 o4 = f2bf(bf2f(e1.x) + fmaxf(fmaf(bf2f(pb.x), sc1.x, sh1.x), 0.f));
            u16 o5 = f2bf(bf2f(e1.y) + fmaxf(fmaf(bf2f(pb.y), sc1.y, sh1.y), 0.f));
            u16 o6 = f2bf(bf2f(e1.z) + fmaxf(fmaf(bf2f(pb.z), sc1.z, sh1.z), 0.f));
            u16 o7 = f2bf(bf2f(e1.w) + fmaxf(fmaf(bf2f(pb.w), sc1.w, sh1.w), 0.f));
            uint4 ov;
            ov.x = (uint32_t)o0 | ((uint32_t)o1 << 16);
            ov.y = (uint32_t)o2 | ((uint32_t)o3 << 16);
            ov.z = (uint32_t)o4 | ((uint32_t)o5 << 16);
            ov.w = (uint32_t)o6 | ((uint32_t)o7 << 16);
            *(uint4*)(gp + i * 8) = ov;
        }
    }
}

// ---------------- BN finalize (edge: 64-slice reduce) ----------------
__global__ void k_bn_final_e(const double* __restrict__ stats_e,
                             const float* __restrict__ g, const float* __restrict__ b,
                             float* __restrict__ scale, float* __restrict__ shift) {
    int j = threadIdx.x;
    double m = 0.0, q = 0.0;
    for (int s = 0; s < 64; ++s) {
        m += stats_e[(size_t)s * 512 + j];
        q += stats_e[(size_t)s * 512 + 256 + j];
    }
    m /= (double)E;
    double var = q / (double)E - m * m;
    if (var < 0.0) var = 0.0;
    float inv = rsqrtf((float)var + 1e-5f);
    float sc = g[j] * inv;
    scale[j] = sc;
    shift[j] = b[j] - (float)m * sc;
}

// ---------------- BN finalize (node, single slice) ----------------
__global__ void k_bn_final(const double* __restrict__ stats, int base,
                           const float* __restrict__ g, const float* __restrict__ b,
                           double cnt, float* __restrict__ scale, float* __restrict__ shift) {
    int j = threadIdx.x;
    double m = stats[base + j] / cnt;
    double var = stats[base + 256 + j] / cnt - m * m;
    if (var < 0.0) var = 0.0;
    float inv = rsqrtf((float)var + 1e-5f);
    float sc = g[j] * inv;
    scale[j] = sc;
    shift[j] = b[j] - (float)m * sc;
}

// ---------------- vie finalize: decode raw max, affine+relu; untouched (isolated) -> 0 ----------------
__global__ void k_vie_final(unsigned int* __restrict__ vie_u,
                            const float* __restrict__ scale, const float* __restrict__ shift) {
    size_t idx = ((size_t)blockIdx.x * 256 + threadIdx.x) * 4;
    int col = (int)(idx & (size_t)(H - 1));
    uint4 u = *(const uint4*)(vie_u + idx);
    float4 sc = *(const float4*)(scale + col);
    float4 sh = *(const float4*)(shift + col);
    float4 o;
    o.x = (u.x == 0u) ? 0.f : fmaxf(fmaf(decf(u.x), sc.x, sh.x), 0.f);
    o.y = (u.y == 0u) ? 0.f : fmaxf(fmaf(decf(u.y), sc.y, sh.y), 0.f);
    o.z = (u.z == 0u) ? 0.f : fmaxf(fmaf(decf(u.z), sc.z, sh.z), 0.f);
    o.w = (u.w == 0u) ? 0.f : fmaxf(fmaf(decf(u.w), sc.w, sh.w), 0.f);
    *(float4*)((float*)vie_u + idx) = o;
}

// ---------------- MFMA fused GRU: h = (1-z)*n + z*v_in, plus BN stats ----------------
template <bool W16>
__global__ __launch_bounds__(256, 2) void k_gru_mfma(
    const float* __restrict__ vie, const u16* __restrict__ vin,
    const u16* __restrict__ wihb, const float* __restrict__ wihf,
    const u16* __restrict__ whhb, const float* __restrict__ whhf,
    const float* __restrict__ bih, const float* __restrict__ bhh,
    u16* __restrict__ hout, double* __restrict__ stats_v)
{
    __shared__ u16 Ae[64][264];   // vie (bf16-staged)
    __shared__ u16 Av[64][264];   // vin
    __shared__ float csum[256], csq[256];
    int t = threadIdx.x;
    int row0 = blockIdx.x * 64;
    int rows = min(64, N - row0);
    int r = t >> 2, q = t & 3;
    if (r < rows) {
        const float* gp = vie + (size_t)(row0 + r) * H + q * 64;
        const u16* hp = vin + (size_t)(row0 + r) * H + q * 64;
#pragma unroll
        for (int i = 0; i < 16; ++i) {
            float4 v = *(const float4*)(gp + i * 4);
            *(ushort4*)&Ae[r][q * 64 + i * 4] = make_ushort4(f2bf(v.x), f2bf(v.y), f2bf(v.z), f2bf(v.w));
        }
#pragma unroll
        for (int i = 0; i < 8; ++i)
            *(uint4*)&Av[r][q * 64 + i * 8] = *(const uint4*)(hp + i * 8);
    } else {
#pragma unroll
        for (int i = 0; i < 8; ++i) {
            *(uint4*)&Ae[r][q * 64 + i * 8] = make_uint4(0, 0, 0, 0);
            *(uint4*)&Av[r][q * 64 + i * 8] = make_uint4(0, 0, 0, 0);
        }
    }
    __syncthreads();
    int w = t >> 6, l = t & 63, lane16 = l & 15, quad = l >> 4;

    for (int g = 0; g < 4; ++g) {
        int j = g * 64 + w * 16 + lane16;
        f32x4 aR[4], aZ[4], aIG[4], aHG[4];
#pragma unroll
        for (int mt = 0; mt < 4; ++mt) {
            aR[mt] = (f32x4){0.f, 0.f, 0.f, 0.f};  aZ[mt] = (f32x4){0.f, 0.f, 0.f, 0.f};
            aIG[mt] = (f32x4){0.f, 0.f, 0.f, 0.f}; aHG[mt] = (f32x4){0.f, 0.f, 0.f, 0.f};
        }
        for (int k0 = 0; k0 < H; k0 += 32) {
            size_t kq = (size_t)k0 + quad * 8;
            bf16x8 ae[4], av[4];
#pragma unroll
            for (int mt = 0; mt < 4; ++mt) {
                ae[mt] = *(const bf16x8*)&Ae[mt * 16 + lane16][k0 + quad * 8];
                av[mt] = *(const bf16x8*)&Av[mt * 16 + lane16][k0 + quad * 8];
            }
            bf16x8 bri = ldb<W16>(wihb, wihf, (size_t)j * H + kq);
            bf16x8 bzi = ldb<W16>(wihb, wihf, (size_t)(H + j) * H + kq);
            bf16x8 bgi = ldb<W16>(wihb, wihf, (size_t)(2 * H + j) * H + kq);
            bf16x8 brh = ldb<W16>(whhb, whhf, (size_t)j * H + kq);
            bf16x8 bzh = ldb<W16>(whhb, whhf, (size_t)(H + j) * H + kq);
            bf16x8 bgh = ldb<W16>(whhb, whhf, (size_t)(2 * H + j) * H + kq);
#pragma unroll
            for (int mt = 0; mt < 4; ++mt) {
                aR[mt]  = __builtin_amdgcn_mfma_f32_16x16x32_bf16(ae[mt], bri, aR[mt], 0, 0, 0);
                aR[mt]  = __builtin_amdgcn_mfma_f32_16x16x32_bf16(av[mt], brh, aR[mt], 0, 0, 0);
                aZ[mt]  = __builtin_amdgcn_mfma_f32_16x16x32_bf16(ae[mt], bzi, aZ[mt], 0, 0, 0);
                aZ[mt]  = __builtin_amdgcn_mfma_f32_16x16x32_bf16(av[mt], bzh, aZ[mt], 0, 0, 0);
                aIG[mt] = __builtin_amdgcn_mfma_f32_16x16x32_bf16(ae[mt], bgi, aIG[mt], 0, 0, 0);
                aHG[mt] = __builtin_amdgcn_mfma_f32_16x16x32_bf16(av[mt], bgh, aHG[mt], 0, 0, 0);
            }
        }
        float br_ = bih[j] + bhh[j];
        float bz_ = bih[H + j] + bhh[H + j];
        float bgi_ = bih[2 * H + j];
        float bgh_ = bhh[2 * H + j];
        float s = 0.f, qq = 0.f;
#pragma unroll
        for (int mt = 0; mt < 4; ++mt)
#pragma unroll
            for (int reg = 0; reg < 4; ++reg) {
                int row = mt * 16 + quad * 4 + reg;
                float rr = sigmf(aR[mt][reg] + br_);
                float zz = sigmf(aZ[mt][reg] + bz_);
                float nn = tanhf_(aIG[mt][reg] + bgi_ + rr * (aHG[mt][reg] + bgh_));
                float vv = bf2f(Av[row][j]);
                float hv = (1.f - zz) * nn + zz * vv;
                if (row < rows) {
                    hout[(size_t)(row0 + row) * H + j] = f2bf(hv);
                    s += hv; qq += hv * hv;
                }
            }
        s  += __shfl_xor(s, 16, 64);  s  += __shfl_xor(s, 32, 64);
        qq += __shfl_xor(qq, 16, 64); qq += __shfl_xor(qq, 32, 64);
        if (quad == 0) { csum[j] = s; csq[j] = qq; }
    }
    __syncthreads();
    atomicAdd(&stats_v[t], (double)csum[t]);
    atomicAdd(&stats_v[256 + t], (double)csq[t]);
}

// ---------------- vertex update: v_in += relu(h*scale+shift) (bf16 rmw) ----------------
__global__ void k_vertex_update(u16* __restrict__ vin, const u16* __restrict__ h,
                                const float* __restrict__ scale, const float* __restrict__ shift) {
    size_t idx = ((size_t)blockIdx.x * 256 + threadIdx.x) * 4;
    int col = (int)(idx & (size_t)(H - 1));
    ushort4 hv = *(const ushort4*)(h + idx);
    float4 sc = *(const float4*)(scale + col);
    float4 sh = *(const float4*)(shift + col);
    ushort4 vv = *(const ushort4*)(vin + idx);
    float o0 = bf2f(vv.x) + fmaxf(fmaf(bf2f(hv.x), sc.x, sh.x), 0.f);
    float o1 = bf2f(vv.y) + fmaxf(fmaf(bf2f(hv.y), sc.y, sh.y), 0.f);
    float o2 = bf2f(vv.z) + fmaxf(fmaf(bf2f(hv.z), sc.z, sh.z), 0.f);
    float o3 = bf2f(vv.w) + fmaxf(fmaf(bf2f(hv.w), sc.w, sh.w), 0.f);
    *(ushort4*)(vin + idx) = make_ushort4(f2bf(o0), f2bf(o1), f2bf(o2), f2bf(o3));
}

// ---------------- final: out[e] = e_in[e] . w_fo + b_fo ----------------
__global__ __launch_bounds__(256) void k_final(const u16* __restrict__ ein,
                                               const float* __restrict__ w_fo, float* __restrict__ out) {
    int t = threadIdx.x;
    int lane = t & 63;
    int w = (blockIdx.x << 2) + (t >> 6);
    float4 wv = *(const float4*)(w_fo + lane * 4);
    float bfo = w_fo[H];
    int e0 = w * 64;
    for (int e = e0; e < e0 + 64; ++e) {
        ushort4 u = *(const ushort4*)(ein + (size_t)e * H + lane * 4);
        float p = bf2f(u.x) * wv.x + bf2f(u.y) * wv.y + bf2f(u.z) * wv.z + bf2f(u.w) * wv.w;
        for (int off = 32; off > 0; off >>= 1) p += __shfl_down(p, off, 64);
        if (lane == 0) out[e] = p + bfo;
    }
}

// ---------------- pipeline ----------------
template <bool W16>
static void run_all(void* const* d_in, void* d_out, void* d_ws, hipStream_t stream) {
    const float* x         = (const float*)d_in[0];
    const float* edge_attr = (const float*)d_in[1];
    const int*   ei        = (const int*)d_in[2];
    const int*   src = ei;
    const int*   dst = ei + E;
    const float* ew  = (const float*)d_in[3];
    const float* eb  = (const float*)d_in[4];
    const float* vw  = (const float*)d_in[5];
    const float* vb  = (const float*)d_in[6];
    const float* Le_w = (const float*)d_in[7];
    // d_in[8] = Le_b : cancels in BN
    const float* Lv_w = (const float*)d_in[9];
    // d_in[10] = Lv_b : cancels in BN
    const float* bne_g = (const float*)d_in[11];
    const float* bne_b = (const float*)d_in[12];
    const float* bnv_g = (const float*)d_in[13];
    const float* bnv_b = (const float*)d_in[14];
    const float* gwih  = (const float*)d_in[15];
    const float* gwhh  = (const float*)d_in[16];
    const float* gbih  = (const float*)d_in[17];
    const float* gbhh  = (const float*)d_in[18];
    const float* fin_w = (const float*)d_in[19];
    const float* fin_b = (const float*)d_in[20];
    const float* out_w = (const float*)d_in[21];
    const float* out_b = (const float*)d_in[22];
    float* out = (float*)d_out;

    const size_t nh = (size_t)N * H, eh = (size_t)E * H;
    char* base = (char*)d_ws;
    size_t off = 0;
    auto alloc = [&](size_t bytes) -> char* {
        char* p = base + off;
        off = (off + bytes + 255) & ~(size_t)255;
        return p;
    };
    float* w_fo = (float*)alloc((H + 1) * sizeof(float));
    u16* v_in = (u16*)alloc(nh * sizeof(u16));
    u16* hbuf = (u16*)alloc(nh * sizeof(u16));
    unsigned int* vie_u = (unsigned int*)alloc(nh * sizeof(unsigned int));
    u16* e_in = (u16*)alloc(eh * sizeof(u16));
    u16* wcomb = (u16*)alloc((size_t)NL * 256 * 512 * sizeof(u16));  // [Le|Lv] bf16 (always)
    double* stats_e = (double*)alloc((size_t)64 * 512 * sizeof(double));
    double* stats_v = (double*)alloc(512 * sizeof(double));
    float* scale_e = (float*)alloc(H * sizeof(float));
    float* shift_e = (float*)alloc(H * sizeof(float));
    float* scale_v = (float*)alloc(H * sizeof(float));
    float* shift_v = (float*)alloc(H * sizeof(float));
    int* curS = (int*)alloc((size_t)N * sizeof(int));
    int* curD = (int*)alloc((size_t)N * sizeof(int));
    int* adjS = (int*)alloc((size_t)E * sizeof(int));
    int* adjD = (int*)alloc((size_t)E * sizeof(int));
    // optional bf16 weight copies (only consumed when W16)
    u16 *wbf_ih = nullptr, *wbf_hh = nullptr, *ew_b = nullptr, *vw_b = nullptr;
    if (W16) {
        wbf_ih = (u16*)alloc((size_t)NL * 3 * H * H * sizeof(u16));
        wbf_hh = (u16*)alloc((size_t)NL * 3 * H * H * sizeof(u16));
        ew_b   = (u16*)alloc((size_t)H * FEAT * sizeof(u16));
        vw_b   = (u16*)alloc((size_t)H * FEAT * sizeof(u16));
    }

    // fused final weights; bf16 weight conversions
    k_fuse_final<<<1, 256, 0, stream>>>(fin_w, fin_b, out_w, out_b, w_fo);
    k_cvt_comb<<<(NL * 256 * 128 + 255) / 256, 256, 0, stream>>>(Le_w, Lv_w, wcomb);
    if (W16) {
        k_cvt_w<<<(NL * 3 * H * H / 4 + 255) / 256, 256, 0, stream>>>(gwih, wbf_ih, NL * 3 * H * H / 4);
        k_cvt_w<<<(NL * 3 * H * H / 4 + 255) / 256, 256, 0, stream>>>(gwhh, wbf_hh, NL * 3 * H * H / 4);
        k_cvt_w<<<(H * FEAT / 4 + 255) / 256, 256, 0, stream>>>(ew, ew_b, H * FEAT / 4);
        k_cvt_w<<<(H * FEAT / 4 + 255) / 256, 256, 0, stream>>>(vw, vw_b, H * FEAT / 4);
    }
    // dual CSR
    k_zero_int<<<(N + 255) / 256, 256, 0, stream>>>(curS, N);
    k_zero_int<<<(N + 255) / 256, 256, 0, stream>>>(curD, N);
    k_hist2<<<E / 256, 256, 0, stream>>>(src, dst, curS, curD);
    k_scan<<<1, 256, 0, stream>>>(curS);
    k_scan<<<1, 256, 0, stream>>>(curD);
    k_fill_pair<<<E / 256, 256, 0, stream>>>(src, dst, curS, curD, adjS, adjD);
    // input projections (MFMA, bf16 out)
    const int ntile = (N + 63) / 64;
    k_proj_mfma<W16><<<ntile, 256, 0, stream>>>(x, vw_b, vw, vb, v_in, N);
    k_proj_mfma<W16><<<E / 64, 256, 0, stream>>>(edge_attr, ew_b, ew, eb, e_in, E);

    const int nstat = 64 * 512 + 512;
    for (int k = 0; k < NL; ++k) {
        k_zero_f64<<<(nstat + 255) / 256, 256, 0, stream>>>(stats_e, nstat);  // stats_v contiguous after
        k_fill_u32<<<(int)(nh / 4 / 256), 256, 0, stream>>>(vie_u, 0u);
        const u16* wck = wcomb + (size_t)k * 256 * 512;
        // dst pass: stats + raw max
        k_edge_mfma<true><<<E / 32, 256, 0, stream>>>(e_in, wck, v_in, src, dst,
                                                      adjD, curD, vie_u, stats_e, nullptr, nullptr, nullptr);
        k_bn_final_e<<<1, 256, 0, stream>>>(stats_e, bne_g + k * H, bne_b + k * H, scale_e, shift_e);
        // src pass: raw max + residual into e_in
        k_edge_mfma<false><<<E / 32, 256, 0, stream>>>(e_in, wck, v_in, src, dst,
                                                       adjS, curS, vie_u, nullptr, scale_e, shift_e, e_in);
        k_vie_final<<<(int)(nh / 4 / 256), 256, 0, stream>>>(vie_u, scale_e, shift_e);
        k_gru_mfma<W16><<<ntile, 256, 0, stream>>>((const float*)vie_u, v_in,
            W16 ? wbf_ih + (size_t)k * 3 * H * H : nullptr, gwih + (size_t)k * 3 * H * H,
            W16 ? wbf_hh + (size_t)k * 3 * H * H : nullptr, gwhh + (size_t)k * 3 * H * H,
            gbih + (size_t)k * 3 * H, gbhh + (size_t)k * 3 * H, hbuf, stats_v);
        k_bn_final<<<1, 256, 0, stream>>>(stats_v, 0, bnv_g + k * H, bnv_b + k * H, (double)N, scale_v, shift_v);
        k_vertex_update<<<(int)(nh / 4 / 256), 256, 0, stream>>>(v_in, hbuf, scale_v, shift_v);
    }
    k_final<<<E / 256, 256, 0, stream>>>(e_in, w_fo, out);
}

// ---------------- host entry ----------------
extern "C" void kernel_launch(void* const* d_in, const int* in_sizes, int n_in,
                              void* d_out, int out_size, void* d_ws, size_t ws_size,
                              hipStream_t stream) {
    (void)in_sizes; (void)n_in; (void)out_size;
    const size_t nh = (size_t)N * H, eh = (size_t)E * H;
    auto rup = [](size_t x) { return (x + 255) & ~(size_t)255; };
    size_t need_base = rup((H + 1) * 4) + 2 * rup(nh * 2) + rup(nh * 4) + rup(eh * 2)
                     + rup((size_t)NL * 256 * 512 * 2) + rup((size_t)64 * 512 * 8) + rup(512 * 8)
                     + 4 * rup(H * 4) + 2 * rup((size_t)N * 4) + 2 * rup((size_t)E * 4);
    size_t need_full = need_base + 2 * rup((size_t)NL * 3 * H * H * 2) + 2 * rup((size_t)H * FEAT * 2);
    if (ws_size == 0 || ws_size >= need_full)
        run_all<true>(d_in, d_out, d_ws, stream);   // bf16 weight copies fit
    else
        run_all<false>(d_in, d_out, d_ws, stream);  // inline fp32->bf16 B-fragment converts
}